// Round 3
// baseline (4324.197 us; speedup 1.0000x reference)
//
#include <hip/hip_runtime.h>
#include <math.h>

#define BATCH 8
#define CH 64
#define HW 96
#define HQ 47
#define LQ 2209         // 47*47
#define LP 2304         // padded to 18*128
#define KD 1600         // 64*25
#define NC9 576         // 64*9
#define NTILE 18        // LP/128 l-tiles
#define CT 32           // c-chunk in brute kernel

// ---------------------------------------------------------------------------
// numpy pairwise sum of squares (blocksize 128, 8 accumulators) — exact
// emulation of numpy's pairwise_sum over a contiguous fp32 axis.
// ---------------------------------------------------------------------------
__device__ float np_pairwise_sq(const float* a, int n) {
#pragma clang fp contract(off)
  if (n <= 128) {
    float r[8];
#pragma unroll
    for (int j = 0; j < 8; ++j) { float x = a[j]; r[j] = x * x; }
    int nm8 = n - (n % 8);
    for (int i = 8; i < nm8; i += 8)
#pragma unroll
      for (int j = 0; j < 8; ++j) { float x = a[i + j]; r[j] = r[j] + x * x; }
    float res = ((r[0] + r[1]) + (r[2] + r[3])) + ((r[4] + r[5]) + (r[6] + r[7]));
    for (int i = nm8; i < n; ++i) { float x = a[i]; res = res + x * x; }
    return res;
  }
  int n2 = n / 2;
  n2 -= n2 % 8;
  float s0 = np_pairwise_sq(a, n2);
  float s1 = np_pairwise_sq(a + n2, n - n2);
  return s0 + s1;
}

// ---------------------------------------------------------------------------
// prep: unfold (k=5,p=1,s=2), L2-normalize with numpy-exact fp32 rounding.
// mode 0 (key):  norm via pairwise-128 (contig axis); mode 1 (query):
// sequential-in-c (middle-axis reduce). rows >= LQ zero-filled.
// ---------------------------------------------------------------------------
__global__ __launch_bounds__(256) void prep_np_kernel(
    const float* __restrict__ src, float* __restrict__ out, int mode) {
  __shared__ float sRaw[KD];
  __shared__ float sDen;
  const int pos = blockIdx.x;
  const int b = blockIdx.y;
  const int t = threadIdx.x;
  const size_t obase = ((size_t)b * LP + pos) * KD;

  if (pos >= LQ) {
    for (int k = t; k < KD; k += 256) out[obase + k] = 0.f;
    return;
  }
  const int y0 = (pos / HQ) * 2 - 1, x0 = (pos % HQ) * 2 - 1;
  for (int k = t; k < KD; k += 256) {
    const int c = k / 25, r = k % 25, kh = r / 5, kw = r % 5;
    const int y = y0 + kh, x = x0 + kw;
    float v = 0.f;
    if (y >= 0 && y < HW && x >= 0 && x < HW)
      v = src[(((size_t)b * CH + c) * HW + y) * HW + x];
    sRaw[k] = v;
  }
  __syncthreads();
  if (t == 0) {
    float ss;
    if (mode == 0) {
      ss = np_pairwise_sq(sRaw, KD);
    } else {
#pragma clang fp contract(off)
      float acc = 0.f;
      for (int k2 = 0; k2 < KD; ++k2) {
        float x = sRaw[k2];
        float p = x * x;
        acc = acc + p;
      }
      ss = acc;
    }
    float nrm = (float)sqrt((double)ss);
    sDen = fmaxf(nrm, 1e-12f);
  }
  __syncthreads();
  const float den = sDen;
  for (int k = t; k < KD; k += 256) out[obase + k] = sRaw[k] / den;
}

// ---------------------------------------------------------------------------
// brute: EXACT fp64 dots of the fp32 normalized arrays, per-tile top-2.
// Block = 128 l x 128 q; thread = 4 q x 16 l.
// ---------------------------------------------------------------------------
__global__ __launch_bounds__(256) void brute64_kernel(
    const float* __restrict__ kn, const float* __restrict__ qn,
    double* __restrict__ tV1, int* __restrict__ tL1,
    double* __restrict__ tV2, int* __restrict__ tL2) {
  __shared__ float sK[128][CT];
  __shared__ float sQ[128][CT + 1];
  __shared__ double sMV1[8][128];
  __shared__ double sMV2[8][128];
  __shared__ int sML1[8][128];
  __shared__ int sML2[8][128];

  const int t = threadIdx.x;
  const int qt = blockIdx.x, lt = blockIdx.y, b = blockIdx.z;
  const int l0 = lt * 128, q0 = qt * 128;
  const int qg = (t & 31) * 4;
  const int lgrp = t >> 5;
  const int lg = lgrp * 16;

  double acc[4][16];
#pragma unroll
  for (int i = 0; i < 4; ++i)
#pragma unroll
    for (int j = 0; j < 16; ++j) acc[i][j] = 0.0;

  for (int c0 = 0; c0 < KD; c0 += CT) {
    for (int idx = t; idx < 128 * CT; idx += 256) {
      const int p = idx >> 5;   // CT == 32
      const int c = idx & 31;
      sK[p][c] = kn[((size_t)(b * LP + l0 + p)) * KD + c0 + c];
      sQ[p][c] = qn[((size_t)(b * LP + q0 + p)) * KD + c0 + c];
    }
    __syncthreads();
    for (int cc = 0; cc < CT; ++cc) {
      double qv[4], kv[16];
#pragma unroll
      for (int i = 0; i < 4; ++i) qv[i] = (double)sQ[qg + i][cc];
#pragma unroll
      for (int j = 0; j < 16; ++j) kv[j] = (double)sK[lg + j][cc];
#pragma unroll
      for (int i = 0; i < 4; ++i)
#pragma unroll
        for (int j = 0; j < 16; ++j)
          acc[i][j] = fma(qv[i], kv[j], acc[i][j]);
    }
    __syncthreads();
  }

  // per-thread top-2 over its 16 l's (ascending l -> first-wins on ties)
#pragma unroll
  for (int i = 0; i < 4; ++i) {
    double v1 = -1e300, v2 = -1e300;
    int l1 = -1, l2 = -1;
#pragma unroll
    for (int j = 0; j < 16; ++j) {
      const int l = l0 + lg + j;
      if (l < LQ) {
        const double v = acc[i][j];
        if (v > v1) { v2 = v1; l2 = l1; v1 = v; l1 = l; }
        else if (v > v2) { v2 = v; l2 = l; }
      }
    }
    sMV1[lgrp][qg + i] = v1; sML1[lgrp][qg + i] = l1;
    sMV2[lgrp][qg + i] = v2; sML2[lgrp][qg + i] = l2;
  }
  __syncthreads();
  if (t < 128) {
    double v1 = sMV1[0][t], v2 = sMV2[0][t];
    int l1 = sML1[0][t], l2 = sML2[0][t];
#pragma unroll
    for (int g = 1; g < 8; ++g) {
      const double b1 = sMV1[g][t], b2 = sMV2[g][t];
      const int a1 = sML1[g][t], a2 = sML2[g][t];
      if (b1 > v1) {
        const double nv2 = (v1 > b2) ? v1 : b2;
        const int nl2 = (v1 > b2) ? l1 : a2;
        v1 = b1; l1 = a1; v2 = nv2; l2 = nl2;
      } else if (b1 > v2) { v2 = b1; l2 = a1; }
    }
    const int q = q0 + t;
    if (q < LQ) {
      const size_t o = ((size_t)b * LP + q) * NTILE + lt;
      tV1[o] = v1; tL1[o] = l1; tV2[o] = v2; tL2[o] = l2;
    }
  }
}

// ---------------------------------------------------------------------------
// finalize: merge 18 tiles -> exact global top-2, then apply the fp32
// bit-tie argmax rule: the reference's R behaves as correctly-rounded fp32
// of the exact dot; rounding is monotone, so its argmax differs from the
// exact argmax IFF fp32(v1)==fp32(v2) bit-exactly AND l2<l1 (np.argmax
// takes the FIRST index attaining the max). No tuned constants.
// ---------------------------------------------------------------------------
__global__ __launch_bounds__(256) void finalize64_kernel(
    const double* __restrict__ tV1, const int* __restrict__ tL1,
    const double* __restrict__ tV2, const int* __restrict__ tL2,
    float* __restrict__ S, int* __restrict__ final_l) {
  const int q = blockIdx.x * 256 + threadIdx.x;
  const int b = blockIdx.z;
  if (q >= LQ) return;
  const size_t base = ((size_t)b * LP + q) * NTILE;
  double v1 = -1e300, v2 = -1e300;
  int l1 = -1, l2 = -1;
  for (int i = 0; i < NTILE; ++i) {
    const double b1 = tV1[base + i], b2 = tV2[base + i];
    const int a1 = tL1[base + i], a2 = tL2[base + i];
    if (b1 > v1) {
      const double nv2 = (v1 > b2) ? v1 : b2;
      const int nl2 = (v1 > b2) ? l1 : a2;
      v1 = b1; l1 = a1; v2 = nv2; l2 = nl2;
    } else if (b1 > v2) { v2 = b1; l2 = a1; }
  }
  const float f1 = (float)v1;
  const float f2 = (float)v2;
  int win = l1;
  if (l2 >= 0 && f2 == f1 && l2 < l1) win = l2;  // fp32 bit-tie, first index wins
  S[b * LQ + q] = f1;
  final_l[b * LQ + q] = win;
}

// ---------------------------------------------------------------------------
// gather: value patches (k=3,p=1,s=1) at argmax positions.
// ---------------------------------------------------------------------------
__global__ __launch_bounds__(256) void gather_kernel(
    const int* __restrict__ final_l, const float* __restrict__ value,
    float* __restrict__ T) {
  const int q = blockIdx.x * 256 + threadIdx.x;
  const int g = blockIdx.y;
  const int b = blockIdx.z;
  if (q >= LQ) return;
  const int l = final_l[b * LQ + q];
  const int y0 = l / HW - 1;
  const int x0 = l % HW - 1;
#pragma unroll
  for (int cc = 0; cc < 36; ++cc) {
    const int c9 = g * 36 + cc;
    const int c = c9 / 9, r = c9 % 9;
    const int kh = r / 3, kw = r % 3;
    const int y = y0 + kh, x = x0 + kw;
    float v = 0.f;
    if (y >= 0 && y < HW && x >= 0 && x < HW)
      v = value[(((size_t)b * CH + c) * HW + y) * HW + x];
    T[((size_t)(b * NC9 + c9)) * LQ + q] = v;
  }
}

// ---------------------------------------------------------------------------
extern "C" void kernel_launch(void* const* d_in, const int* in_sizes, int n_in,
                              void* d_out, int out_size, void* d_ws,
                              size_t ws_size, hipStream_t stream) {
  const float* queue = (const float*)d_in[0];
  const float* key   = (const float*)d_in[1];
  const float* value = (const float*)d_in[2];
  float* S = (float*)d_out;
  float* T = S + (size_t)BATCH * LQ;

  char* ws = (char*)d_ws;
  const size_t arr = (size_t)BATCH * LP * KD * sizeof(float);  // 117,964,800 B
  float* kn = (float*)(ws);
  float* qn = (float*)(ws + arr);
  size_t off = 2 * arr;
  const size_t nt = (size_t)BATCH * LP * NTILE;  // 331,776 entries
  double* tV1 = (double*)(ws + off); off += nt * 8;
  double* tV2 = (double*)(ws + off); off += nt * 8;
  int* tL1 = (int*)(ws + off); off += nt * 4;
  int* tL2 = (int*)(ws + off); off += nt * 4;
  int* final_l = (int*)(ws + off);

  prep_np_kernel<<<dim3(LP, BATCH), 256, 0, stream>>>(key, kn, 0);
  prep_np_kernel<<<dim3(LP, BATCH), 256, 0, stream>>>(queue, qn, 1);
  brute64_kernel<<<dim3(LP / 128, LP / 128, BATCH), 256, 0, stream>>>(
      kn, qn, tV1, tL1, tV2, tL2);
  finalize64_kernel<<<dim3((LQ + 255) / 256, 1, BATCH), 256, 0, stream>>>(
      tV1, tL1, tV2, tL2, S, final_l);
  gather_kernel<<<dim3((LQ + 255) / 256, 16, BATCH), 256, 0, stream>>>(
      final_l, value, T);
}

// Round 4
// 3249.631 us; speedup vs baseline: 1.3307x; 1.3307x over previous
//
#include <hip/hip_runtime.h>
#include <math.h>

#define BATCH 8
#define CH 64
#define HW 96
#define HQ 47
#define LQ 2209         // 47*47
#define LP 2304         // padded to 18*128
#define KD 1600         // 64*25
#define NC9 576         // 64*9
#define NTILE 18        // LP/128 l-tiles
#define CT 32           // c-chunk in brute kernel
#define MARGIN 6e-5f    // >= 2*eps_screen(2.5e-5, Hoeffding e^-217) + fp32 ulp

// ---------------------------------------------------------------------------
// numpy pairwise sum of squares (blocksize 128, 8 accumulators) — exact
// emulation of numpy's pairwise_sum over a contiguous fp32 axis.
// ---------------------------------------------------------------------------
__device__ float np_pairwise_sq(const float* a, int n) {
#pragma clang fp contract(off)
  if (n <= 128) {
    float r[8];
#pragma unroll
    for (int j = 0; j < 8; ++j) { float x = a[j]; r[j] = x * x; }
    int nm8 = n - (n % 8);
    for (int i = 8; i < nm8; i += 8)
#pragma unroll
      for (int j = 0; j < 8; ++j) { float x = a[i + j]; r[j] = r[j] + x * x; }
    float res = ((r[0] + r[1]) + (r[2] + r[3])) + ((r[4] + r[5]) + (r[6] + r[7]));
    for (int i = nm8; i < n; ++i) { float x = a[i]; res = res + x * x; }
    return res;
  }
  int n2 = n / 2;
  n2 -= n2 % 8;
  float s0 = np_pairwise_sq(a, n2);
  float s1 = np_pairwise_sq(a + n2, n - n2);
  return s0 + s1;
}

// ---------------------------------------------------------------------------
// prep: unfold (k=5,p=1,s=2), L2-normalize with numpy-exact fp32 rounding.
// mode 0 (key):  norm via pairwise-128 (contig axis); mode 1 (query):
// sequential-in-c (middle-axis reduce). rows >= LQ zero-filled.
// ---------------------------------------------------------------------------
__global__ __launch_bounds__(256) void prep_np_kernel(
    const float* __restrict__ src, float* __restrict__ out, int mode) {
  __shared__ float sRaw[KD];
  __shared__ float sDen;
  const int pos = blockIdx.x;
  const int b = blockIdx.y;
  const int t = threadIdx.x;
  const size_t obase = ((size_t)b * LP + pos) * KD;

  if (pos >= LQ) {
    for (int k = t; k < KD; k += 256) out[obase + k] = 0.f;
    return;
  }
  const int y0 = (pos / HQ) * 2 - 1, x0 = (pos % HQ) * 2 - 1;
  for (int k = t; k < KD; k += 256) {
    const int c = k / 25, r = k % 25, kh = r / 5, kw = r % 5;
    const int y = y0 + kh, x = x0 + kw;
    float v = 0.f;
    if (y >= 0 && y < HW && x >= 0 && x < HW)
      v = src[(((size_t)b * CH + c) * HW + y) * HW + x];
    sRaw[k] = v;
  }
  __syncthreads();
  if (t == 0) {
    float ss;
    if (mode == 0) {
      ss = np_pairwise_sq(sRaw, KD);
    } else {
#pragma clang fp contract(off)
      float acc = 0.f;
      for (int k2 = 0; k2 < KD; ++k2) {
        float x = sRaw[k2];
        float p = x * x;
        acc = acc + p;
      }
      ss = acc;
    }
    float nrm = (float)sqrt((double)ss);
    sDen = fmaxf(nrm, 1e-12f);
  }
  __syncthreads();
  const float den = sDen;
  for (int k = t; k < KD; k += 256) out[obase + k] = sRaw[k] / den;
}

// ---------------------------------------------------------------------------
// brute32: fp32 SCREENING pass. Same tiling as the old fp64 brute, but
// fp32 fmaf accumulation (2cy vs 4cy, no f64 cvt) and sQ transposed to
// [CT][132] so the per-thread q-fragment is ONE lane-contiguous float4
// read (conflict-free) instead of four 4-way-conflicted scalar reads.
// Per-dot |approx - exact| <= 2.5e-5 (Hoeffding, e^-217). Per-tile top-2.
// ---------------------------------------------------------------------------
__global__ __launch_bounds__(256) void brute32_kernel(
    const float* __restrict__ kn, const float* __restrict__ qn,
    float* __restrict__ tV1, int* __restrict__ tL1,
    float* __restrict__ tV2, int* __restrict__ tL2) {
  __shared__ float sK[128][CT];      // row-major: writes bank-free, reads broadcast
  __shared__ float sQ[CT][132];      // transposed: float4 reads, rows 16B-aligned
  __shared__ float sMV1[8][128];
  __shared__ float sMV2[8][128];
  __shared__ int sML1[8][128];
  __shared__ int sML2[8][128];

  const int t = threadIdx.x;
  const int qt = blockIdx.x, lt = blockIdx.y, b = blockIdx.z;
  const int l0 = lt * 128, q0 = qt * 128;
  const int qg = (t & 31) * 4;
  const int lgrp = t >> 5;
  const int lg = lgrp * 16;

  float acc[4][16];
#pragma unroll
  for (int i = 0; i < 4; ++i)
#pragma unroll
    for (int j = 0; j < 16; ++j) acc[i][j] = 0.f;

  for (int c0 = 0; c0 < KD; c0 += CT) {
    for (int idx = t; idx < 128 * CT; idx += 256) {
      const int p = idx >> 5;   // CT == 32
      const int c = idx & 31;
      sK[p][c] = kn[((size_t)(b * LP + l0 + p)) * KD + c0 + c];
      sQ[c][p] = qn[((size_t)(b * LP + q0 + p)) * KD + c0 + c];
    }
    __syncthreads();
    for (int cc = 0; cc < CT; ++cc) {
      const float4 q4 = *reinterpret_cast<const float4*>(&sQ[cc][qg]);
      const float qv[4] = {q4.x, q4.y, q4.z, q4.w};
#pragma unroll
      for (int j = 0; j < 16; ++j) {
        const float kvj = sK[lg + j][cc];
#pragma unroll
        for (int i = 0; i < 4; ++i)
          acc[i][j] = fmaf(qv[i], kvj, acc[i][j]);
      }
    }
    __syncthreads();
  }

  // per-thread top-2 over its 16 l's (ascending l -> first-wins on ties)
#pragma unroll
  for (int i = 0; i < 4; ++i) {
    float v1 = -1e30f, v2 = -1e30f;
    int l1 = -1, l2 = -1;
#pragma unroll
    for (int j = 0; j < 16; ++j) {
      const int l = l0 + lg + j;
      if (l < LQ) {
        const float v = acc[i][j];
        if (v > v1) { v2 = v1; l2 = l1; v1 = v; l1 = l; }
        else if (v > v2) { v2 = v; l2 = l; }
      }
    }
    sMV1[lgrp][qg + i] = v1; sML1[lgrp][qg + i] = l1;
    sMV2[lgrp][qg + i] = v2; sML2[lgrp][qg + i] = l2;
  }
  __syncthreads();
  if (t < 128) {
    float v1 = sMV1[0][t], v2 = sMV2[0][t];
    int l1 = sML1[0][t], l2 = sML2[0][t];
#pragma unroll
    for (int g = 1; g < 8; ++g) {
      const float b1 = sMV1[g][t], b2 = sMV2[g][t];
      const int a1 = sML1[g][t], a2 = sML2[g][t];
      if (b1 > v1) {
        const float nv2 = (v1 > b2) ? v1 : b2;
        const int nl2 = (v1 > b2) ? l1 : a2;
        v1 = b1; l1 = a1; v2 = nv2; l2 = nl2;
      } else if (b1 > v2) { v2 = b1; l2 = a1; }
    }
    const int q = q0 + t;
    if (q < LQ) {
      const size_t o = ((size_t)b * LP + q) * NTILE + lt;
      tV1[o] = v1; tL1[o] = l1; tV2[o] = v2; tL2[o] = l2;
    }
  }
}

// ---------------------------------------------------------------------------
// finalize32: merge 18 tiles -> approx top-2. Gap >= MARGIN guarantees the
// stored l1 is both the exact and the fp32-rounded argmax (screening error
// bound + union-of-candidates argument). Otherwise flag the query for
// exact refinement. Provisional S/final_l written either way.
// ---------------------------------------------------------------------------
__global__ __launch_bounds__(256) void finalize32_kernel(
    const float* __restrict__ tV1, const int* __restrict__ tL1,
    const float* __restrict__ tV2, const int* __restrict__ tL2,
    float* __restrict__ S, int* __restrict__ final_l,
    int* __restrict__ flag_list, int* __restrict__ flag_cnt) {
  const int q = blockIdx.x * 256 + threadIdx.x;
  const int b = blockIdx.z;
  if (q >= LQ) return;
  const size_t base = ((size_t)b * LP + q) * NTILE;
  float v1 = -1e30f, v2 = -1e30f;
  int l1 = -1, l2 = -1;
  for (int i = 0; i < NTILE; ++i) {
    const float b1 = tV1[base + i], b2 = tV2[base + i];
    const int a1 = tL1[base + i], a2 = tL2[base + i];
    if (b1 > v1) {
      const float nv2 = (v1 > b2) ? v1 : b2;
      const int nl2 = (v1 > b2) ? l1 : a2;
      v1 = b1; l1 = a1; v2 = nv2; l2 = nl2;
    } else if (b1 > v2) { v2 = b1; l2 = a1; }
  }
  S[b * LQ + q] = v1;
  final_l[b * LQ + q] = l1;
  if (l2 >= 0 && (v1 - v2) < MARGIN) {
    const int slot = atomicAdd(flag_cnt, 1);
    flag_list[slot] = b * LQ + q;
  }
}

// ---------------------------------------------------------------------------
// refine: for flagged queries, recompute the ENTIRE row of exact fp64 dots
// and take np.argmax over the fp32-rounded values directly (first-index
// tie rule). Unconditionally correct regardless of screening accuracy.
// Static grid (graph-safe); count read on device.
// ---------------------------------------------------------------------------
__global__ __launch_bounds__(256) void refine_kernel(
    const int* __restrict__ flag_list, const int* __restrict__ flag_cnt,
    const float* __restrict__ kn, const float* __restrict__ qn,
    float* __restrict__ S, int* __restrict__ final_l) {
  __shared__ float sQrow[KD];
  __shared__ float sF[256];
  __shared__ int sL[256];
  const int n = *flag_cnt;
  const int t = threadIdx.x;
  for (int e = blockIdx.x; e < n; e += gridDim.x) {
    const int bq = flag_list[e];
    const int b = bq / LQ, q = bq % LQ;
    __syncthreads();  // protect sQrow reuse across iterations
    for (int k = t; k < KD; k += 256)
      sQrow[k] = qn[((size_t)b * LP + q) * KD + k];
    __syncthreads();
    float bf = -1e30f; int bl = -1;
    for (int l = t; l < LQ; l += 256) {   // ascending l per thread
      const float* kr = kn + ((size_t)b * LP + l) * KD;
      double acc = 0.0;
      for (int c = 0; c < KD; ++c)
        acc = fma((double)kr[c], (double)sQrow[c], acc);
      const float f = (float)acc;         // fp32-rounded exact dot
      if (f > bf) { bf = f; bl = l; }     // strict > keeps first index
    }
    sF[t] = bf; sL[t] = bl;
    __syncthreads();
    for (int s = 128; s > 0; s >>= 1) {
      if (t < s) {
        const float of = sF[t + s]; const int ol = sL[t + s];
        if (of > sF[t] || (of == sF[t] && ol < sL[t])) { sF[t] = of; sL[t] = ol; }
      }
      __syncthreads();
    }
    if (t == 0) { S[b * LQ + q] = sF[0]; final_l[b * LQ + q] = sL[0]; }
  }
}

// ---------------------------------------------------------------------------
// gather: value patches (k=3,p=1,s=1) at argmax positions.
// ---------------------------------------------------------------------------
__global__ __launch_bounds__(256) void gather_kernel(
    const int* __restrict__ final_l, const float* __restrict__ value,
    float* __restrict__ T) {
  const int q = blockIdx.x * 256 + threadIdx.x;
  const int g = blockIdx.y;
  const int b = blockIdx.z;
  if (q >= LQ) return;
  const int l = final_l[b * LQ + q];
  const int y0 = l / HW - 1;
  const int x0 = l % HW - 1;
#pragma unroll
  for (int cc = 0; cc < 36; ++cc) {
    const int c9 = g * 36 + cc;
    const int c = c9 / 9, r = c9 % 9;
    const int kh = r / 3, kw = r % 3;
    const int y = y0 + kh, x = x0 + kw;
    float v = 0.f;
    if (y >= 0 && y < HW && x >= 0 && x < HW)
      v = value[(((size_t)b * CH + c) * HW + y) * HW + x];
    T[((size_t)(b * NC9 + c9)) * LQ + q] = v;
  }
}

// ---------------------------------------------------------------------------
extern "C" void kernel_launch(void* const* d_in, const int* in_sizes, int n_in,
                              void* d_out, int out_size, void* d_ws,
                              size_t ws_size, hipStream_t stream) {
  const float* queue = (const float*)d_in[0];
  const float* key   = (const float*)d_in[1];
  const float* value = (const float*)d_in[2];
  float* S = (float*)d_out;
  float* T = S + (size_t)BATCH * LQ;

  char* ws = (char*)d_ws;
  const size_t arr = (size_t)BATCH * LP * KD * sizeof(float);  // 117,964,800 B
  float* kn = (float*)(ws);
  float* qn = (float*)(ws + arr);
  size_t off = 2 * arr;
  const size_t nt = (size_t)BATCH * LP * NTILE;  // 331,776 entries
  float* tV1 = (float*)(ws + off); off += nt * 4;
  float* tV2 = (float*)(ws + off); off += nt * 4;
  int* tL1 = (int*)(ws + off); off += nt * 4;
  int* tL2 = (int*)(ws + off); off += nt * 4;
  int* final_l = (int*)(ws + off); off += (size_t)BATCH * LQ * 4;
  int* flag_list = (int*)(ws + off); off += (size_t)BATCH * LQ * 4;
  // align counter to 256B
  off = (off + 255) & ~(size_t)255;
  int* flag_cnt = (int*)(ws + off);

  hipMemsetAsync(flag_cnt, 0, sizeof(int), stream);
  prep_np_kernel<<<dim3(LP, BATCH), 256, 0, stream>>>(key, kn, 0);
  prep_np_kernel<<<dim3(LP, BATCH), 256, 0, stream>>>(queue, qn, 1);
  brute32_kernel<<<dim3(LP / 128, LP / 128, BATCH), 256, 0, stream>>>(
      kn, qn, tV1, tL1, tV2, tL2);
  finalize32_kernel<<<dim3((LQ + 255) / 256, 1, BATCH), 256, 0, stream>>>(
      tV1, tL1, tV2, tL2, S, final_l, flag_list, flag_cnt);
  refine_kernel<<<dim3(512), 256, 0, stream>>>(
      flag_list, flag_cnt, kn, qn, S, final_l);
  gather_kernel<<<dim3((LQ + 255) / 256, 16, BATCH), 256, 0, stream>>>(
      final_l, value, T);
}